// Round 1
// 2334.128 us; speedup vs baseline: 1.1324x; 1.1324x over previous
//
#include <hip/hip_runtime.h>
#include <math.h>

// MultiRNNCell: 2-layer LSTM-imputation scan. B=64, T=128, D=256, H=1024.
// R9: fold est into L0 blocks + batch-halve (m-split) everything.
//  - est = h @ Wout^T shares the h pull with L0's h @ Whh0^T: each L0 block
//    carries a 4-col Wout slice (compact, col-replicated frags, 8 KB LDS) and
//    computes est with 1 extra MFMA/kstep. Dedicated est blocks + their
//    128 KB/step pull + one full hop are eliminated; the est->imputed
//    exchange payload is 512 B/block.
//  - 256 blocks = 128 L0est + 128 L1, each owning a 32-row batch half:
//    every bulk pull halves (h/h0 64 KB, imputed 16 KB). 4 waves/block =
//    2 m-tiles x 2 K-halves, partial sums reduced through LDS.
//  - chain/step: fL1 -> [L0est: pull h(half) || est] -> fE -> [L0est: pull
//    imputed(half)] -> fL0 -> [L1: pull h0(half)] -> fL1(t+1).
//  - ring buffers, sc0 sc1 write-through + vmcnt drain, relaxed agent flags
//    ==1 vs 0xAA poison, XCD-stagger rotation: all kept from R8.
// 256 blocks x 256 thr, 134 KB LDS -> 1 block/CU, full chip.

#define B_ 64
#define T_ 128
#define D_ 256
#define H_ 1024

#define KS0 40          // layer0 frag ksteps: 0-7 imputed (D=256), 8-39 h (H=1024)
#define KS1 32          // layer1 ksteps (H=1024)

#define RS_H   ((size_t)B_ * H_)   // 128 KB per ring slot
#define RS_IMP ((size_t)B_ * D_)   // 32 KB per ring slot

typedef __attribute__((ext_vector_type(8))) short short8;   // 8 bf16
typedef __attribute__((ext_vector_type(4))) float floatx4;  // MFMA C/D

__device__ __forceinline__ unsigned short f2bf(float x) {
    union { float f; unsigned u; } v; v.f = x;
    unsigned r = v.u + 0x7fffu + ((v.u >> 16) & 1u);  // RNE
    return (unsigned short)(r >> 16);
}
__device__ __forceinline__ float sigmoidf_(float x) { return 1.0f / (1.0f + expf(-x)); }

// write-through 2B store to the MALL coherence point (bypasses L1+L2)
__device__ __forceinline__ void st_short_sc(unsigned short* p, unsigned v) {
    asm volatile("global_store_short %0, %1, off sc0 sc1"
                 :: "v"(p), "v"(v) : "memory");
}
__device__ __forceinline__ void vm_drain() {
    asm volatile("s_waitcnt vmcnt(0)" ::: "memory");
}

__device__ __forceinline__ void wait_ready(const int* flags, int P) {
    if ((int)threadIdx.x < P) {
        while (__hip_atomic_load(flags + threadIdx.x, __ATOMIC_RELAXED,
                                 __HIP_MEMORY_SCOPE_AGENT) != 1) {}
    }
    __syncthreads();
}
__device__ __forceinline__ void signal_flag(int* flag) {
    __syncthreads();    // all waves' sc1 stores drained (vm_drain) before this
    if (threadIdx.x == 0)
        __hip_atomic_store(flag, 1, __ATOMIC_RELAXED, __HIP_MEMORY_SCOPE_AGENT);
}

#define MFMA __builtin_amdgcn_mfma_f32_16x16x32_bf16

__global__ __launch_bounds__(256, 1) void k_fused(
    const float* __restrict__ Wih0, const float* __restrict__ Whh0,
    const float* __restrict__ bih0, const float* __restrict__ bhh0,
    const float* __restrict__ Wih1, const float* __restrict__ Whh1,
    const float* __restrict__ bih1, const float* __restrict__ bhh1,
    const float* __restrict__ Wout, const float* __restrict__ bout,
    const float* __restrict__ X, const float* __restrict__ Mm,
    unsigned short* __restrict__ hR,    // (T_+1) slots
    unsigned short* __restrict__ h0R,   // T_ slots
    unsigned short* __restrict__ impR,  // T_ slots
    int* __restrict__ fL1, int* __restrict__ fL0, int* __restrict__ fE,
    float* __restrict__ out)
{
    __shared__ unsigned short ldsW[3 * KS0 * 64 * 8];   // 120 KB weight frags
    __shared__ unsigned short ldsWo[32 * 16 * 8];       // 8 KB compact Wout (4 cols)
    __shared__ float          red[2 * 64 * 12];         // 6 KB K-half reduce

    const int tid  = threadIdx.x;
    const int lane = tid & 63;
    const int wv   = tid >> 6;
    const int mt   = wv & 1;         // m-tile within the block's 32-row half
    const int kh   = wv >> 1;        // K-half this wave accumulates
    const int r16  = lane & 15, q = lane >> 4;
    const int bx   = blockIdx.x;
    const int rot  = (bx >> 3) & 7;  // XCD-local stagger (bx%8 = XCD id)
    const unsigned short* lfrag = ldsW + lane * 8;   // + fragIdx*512

    if (bx < 128) {
        // =============== combined layer-0 + est blocks ===============
        const int j  = bx & 63;          // gate n-tile (cols 16j..16j+16)
        const int mh = bx >> 6;          // batch half (rows 32mh..32mh+32)
        const int rowA = mh * 32 + mt * 16 + r16;   // A-frag row for this wave
        {   // one-time: Wih0/Whh0 -> bf16 LDS frags (gates i,g,o; dead f removed)
            int n0 = j * 16;
            for (int idx = wv; idx < 3 * KS0; idx += 4) {
                int gi = idx / KS0, k = idx % KS0;
                int grow = (gi == 0) ? 0 : (gi == 1 ? 2 * H_ : 3 * H_);
                int row = grow + n0 + r16;
                const float* src = (k < 8) ? (Wih0 + (size_t)row * D_ + k * 32 + q * 8)
                                           : (Whh0 + (size_t)row * H_ + (k - 8) * 32 + q * 8);
                short8 w;
                #pragma unroll
                for (int e = 0; e < 8; ++e) w[e] = (short)f2bf(src[e]);
                *(short8*)(ldsW + ((size_t)idx * 64 + lane) * 8) = w;
            }
            // compact Wout slice: 4 est cols (dd = 4j..4j+3), slot = kk*16+c*4+q
            for (int s = tid; s < 512; s += 256) {
                int kk = s >> 4, c = (s >> 2) & 3, qq = s & 3;
                const float* src = Wout + (size_t)(4 * j + c) * H_ + kk * 32 + qq * 8;
                short8 w;
                #pragma unroll
                for (int e = 0; e < 8; ++e) w[e] = (short)f2bf(src[e]);
                *(short8*)(ldsWo + (size_t)s * 8) = w;
            }
        }
        __syncthreads();

        const int n = j * 16 + r16;
        const float bi = bih0[n] + bhh0[n];
        const float bg = bih0[2 * H_ + n] + bhh0[2 * H_ + n];
        const float bo = bih0[3 * H_ + n] + bhh0[3 * H_ + n];
        const int dd = 4 * j + (r16 & 3);           // est col (replicated x4)
        const float bout_d = bout[dd];
        // col-replicated read -> 4-lane broadcast, no predication needed;
        // acc cols r16>=4 are duplicates, only r16<4 lanes store.
        const unsigned short* wofrag = ldsWo + ((r16 & 3) * 4 + q) * 8;

        for (int t = 0; t < T_; ++t) {
            float xv[4], mv[4];   // prefetch inputs before waiting
            if (kh == 0) {
                #pragma unroll
                for (int r = 0; r < 4; ++r) {
                    int bb = mh * 32 + mt * 16 + q * 4 + r;
                    xv[r] = X [((size_t)bb * T_ + t) * D_ + dd];
                    mv[r] = Mm[((size_t)bb * T_ + t) * D_ + dd];
                }
            }
            asm volatile("" ::: "memory");
            wait_ready(fL1 + ((size_t)t * 2 + mh) * 64, 64);   // h(t-1) half ready
            floatx4 ai = {0.f,0.f,0.f,0.f}, ag = ai, ao = ai, ae = ai;
            {   // h-part (this wave: 16 of 32 ksteps) + folded est MFMA;
                // rotated start -> cooperative XCD first-touch
                const unsigned short* aB = hR + (size_t)t * RS_H + (size_t)rowA * H_ + q * 8;
                #pragma unroll
                for (int k = 0; k < 16; ++k) {
                    int kk = kh * 16 + ((k + rot * 2) & 15);
                    short8 a = *(const short8*)(aB + kk * 32);
                    ai = MFMA(a, *(const short8*)(lfrag + (0 * KS0 + 8 + kk) * 512), ai, 0,0,0);
                    ag = MFMA(a, *(const short8*)(lfrag + (1 * KS0 + 8 + kk) * 512), ag, 0,0,0);
                    ao = MFMA(a, *(const short8*)(lfrag + (2 * KS0 + 8 + kk) * 512), ao, 0,0,0);
                    ae = MFMA(a, *(const short8*)(wofrag + kk * 128), ae, 0,0,0);
                }
            }
            // est K-half reduce (R1) -> imputed publish
            if (kh == 1) {
                float* rp = red + ((size_t)mt * 64 + lane) * 4;
                #pragma unroll
                for (int r = 0; r < 4; ++r) rp[r] = ae[r];
            }
            __syncthreads();
            float estv[4];
            if (kh == 0) {
                const float* rp = red + ((size_t)mt * 64 + lane) * 4;
                unsigned short* iS = impR + (size_t)t * RS_IMP;
                #pragma unroll
                for (int r = 0; r < 4; ++r) estv[r] = ae[r] + rp[r] + bout_d;
                if (r16 < 4) {
                    #pragma unroll
                    for (int r = 0; r < 4; ++r) {
                        int bb = mh * 32 + mt * 16 + q * 4 + r;
                        float imp = mv[r] * xv[r] + (1.0f - mv[r]) * estv[r];
                        st_short_sc(&iS[(size_t)bb * D_ + dd], (unsigned)f2bf(imp));
                    }
                }
                vm_drain();
            }
            signal_flag(fE + ((size_t)t * 2 + mh) * 64 + j);
            // out est write AFTER the signal: off the critical chain
            if (kh == 0 && r16 < 4 && t >= 1) {
                #pragma unroll
                for (int r = 0; r < 4; ++r) {
                    int bb = mh * 32 + mt * 16 + q * 4 + r;
                    out[((size_t)bb * T_ + (t - 1)) * D_ + dd] = estv[r];
                }
            }
            wait_ready(fE + ((size_t)t * 2 + mh) * 64, 64);    // imputed half ready
            {   // imputed part (this wave: 4 of 8 ksteps)
                const unsigned short* aB = impR + (size_t)t * RS_IMP + (size_t)rowA * D_ + q * 8;
                #pragma unroll
                for (int k = 0; k < 4; ++k) {
                    int kk = kh * 4 + ((k + rot) & 3);
                    short8 a = *(const short8*)(aB + kk * 32);
                    ai = MFMA(a, *(const short8*)(lfrag + (0 * KS0 + kk) * 512), ai, 0,0,0);
                    ag = MFMA(a, *(const short8*)(lfrag + (1 * KS0 + kk) * 512), ag, 0,0,0);
                    ao = MFMA(a, *(const short8*)(lfrag + (2 * KS0 + kk) * 512), ao, 0,0,0);
                }
            }
            // gate K-half reduce (R2) -> h0 epilogue
            if (kh == 1) {
                float* rp = red + ((size_t)mt * 64 + lane) * 12;
                #pragma unroll
                for (int r = 0; r < 4; ++r) { rp[r] = ai[r]; rp[4 + r] = ag[r]; rp[8 + r] = ao[r]; }
            }
            __syncthreads();
            if (kh == 0) {
                const float* rp = red + ((size_t)mt * 64 + lane) * 12;
                unsigned short* h0S = h0R + (size_t)t * RS_H;
                #pragma unroll
                for (int r = 0; r < 4; ++r) {
                    int bb = mh * 32 + mt * 16 + q * 4 + r;
                    float c = sigmoidf_(ai[r] + rp[r] + bi) * tanhf(ag[r] + rp[4 + r] + bg);
                    float h = sigmoidf_(ao[r] + rp[8 + r] + bo) * tanhf(c);
                    st_short_sc(&h0S[(size_t)bb * H_ + n], (unsigned)f2bf(h));
                }
                vm_drain();
            }
            signal_flag(fL0 + ((size_t)t * 2 + mh) * 64 + j);
        }
        // final projection: est from h(T-1) (slot T_) -> out[:, T-1, :]
        wait_ready(fL1 + ((size_t)T_ * 2 + mh) * 64, 64);
        floatx4 ae = {0.f,0.f,0.f,0.f};
        const unsigned short* aB = hR + (size_t)T_ * RS_H + (size_t)rowA * H_ + q * 8;
        #pragma unroll
        for (int k = 0; k < 16; ++k) {
            int kk = kh * 16 + ((k + rot * 2) & 15);
            short8 a = *(const short8*)(aB + kk * 32);
            ae = MFMA(a, *(const short8*)(wofrag + kk * 128), ae, 0,0,0);
        }
        if (kh == 1) {
            float* rp = red + ((size_t)mt * 64 + lane) * 4;
            #pragma unroll
            for (int r = 0; r < 4; ++r) rp[r] = ae[r];
        }
        __syncthreads();
        if (kh == 0 && r16 < 4) {
            const float* rp = red + ((size_t)mt * 64 + lane) * 4;
            #pragma unroll
            for (int r = 0; r < 4; ++r) {
                int bb = mh * 32 + mt * 16 + q * 4 + r;
                out[((size_t)bb * T_ + (T_ - 1)) * D_ + dd] = ae[r] + rp[r] + bout_d;
            }
        }
    } else {
        // =============== layer-1 blocks ===============
        const int i  = bx - 128;
        const int j1 = i & 63;           // n-tile
        const int mh = i >> 6;           // batch half
        const int rowA = mh * 32 + mt * 16 + r16;
        {   // one-time: folded W1 = Wih1+Whh1 -> bf16 LDS frags
            int n0 = j1 * 16;
            for (int idx = wv; idx < 3 * KS1; idx += 4) {
                int gi = idx / KS1, k = idx % KS1;
                int grow = (gi == 0) ? 0 : (gi == 1 ? 2 * H_ : 3 * H_);
                size_t o = (size_t)(grow + n0 + r16) * H_ + k * 32 + q * 8;
                short8 w;
                #pragma unroll
                for (int e = 0; e < 8; ++e) w[e] = (short)f2bf(Wih1[o + e] + Whh1[o + e]);
                *(short8*)(ldsW + ((size_t)idx * 64 + lane) * 8) = w;
            }
        }
        __syncthreads();
        const int n = j1 * 16 + r16;
        const float bi = bih1[n] + bhh1[n];
        const float bg = bih1[2 * H_ + n] + bhh1[2 * H_ + n];
        const float bo = bih1[3 * H_ + n] + bhh1[3 * H_ + n];
        // h(-1) = 0 -> zeros into hR slot 0 (this block's 32x16 slice), flag it
        if (kh == 0) {
            #pragma unroll
            for (int r = 0; r < 4; ++r) {
                int bb = mh * 32 + mt * 16 + q * 4 + r;
                st_short_sc(&hR[(size_t)bb * H_ + n], 0u);
            }
            vm_drain();
        }
        signal_flag(fL1 + (size_t)mh * 64 + j1);
        for (int t = 0; t < T_; ++t) {
            wait_ready(fL0 + ((size_t)t * 2 + mh) * 64, 64);   // h0(t) half ready
            floatx4 li = {0.f,0.f,0.f,0.f}, lg = li, lo = li;
            const unsigned short* aB = h0R + (size_t)t * RS_H + (size_t)rowA * H_ + q * 8;
            #pragma unroll
            for (int k = 0; k < 16; ++k) {
                int kk = kh * 16 + ((k + rot * 2) & 15);
                short8 a = *(const short8*)(aB + kk * 32);
                li = MFMA(a, *(const short8*)(lfrag + (0 * KS1 + kk) * 512), li, 0,0,0);
                lg = MFMA(a, *(const short8*)(lfrag + (1 * KS1 + kk) * 512), lg, 0,0,0);
                lo = MFMA(a, *(const short8*)(lfrag + (2 * KS1 + kk) * 512), lo, 0,0,0);
            }
            if (kh == 1) {
                float* rp = red + ((size_t)mt * 64 + lane) * 12;
                #pragma unroll
                for (int r = 0; r < 4; ++r) { rp[r] = li[r]; rp[4 + r] = lg[r]; rp[8 + r] = lo[r]; }
            }
            __syncthreads();
            float hv[4];
            if (kh == 0) {
                const float* rp = red + ((size_t)mt * 64 + lane) * 12;
                unsigned short* hS = hR + (size_t)(t + 1) * RS_H;
                #pragma unroll
                for (int r = 0; r < 4; ++r) {
                    int bb = mh * 32 + mt * 16 + q * 4 + r;
                    float c = sigmoidf_(li[r] + rp[r] + bi) * tanhf(lg[r] + rp[4 + r] + bg);
                    hv[r] = sigmoidf_(lo[r] + rp[8 + r] + bo) * tanhf(c);
                    st_short_sc(&hS[(size_t)bb * H_ + n], (unsigned)f2bf(hv[r]));
                }
                vm_drain();
            }
            signal_flag(fL1 + ((size_t)(t + 1) * 2 + mh) * 64 + j1);
            if (t == T_ - 1 && kh == 0) {   // h_final, off the chain
                #pragma unroll
                for (int r = 0; r < 4; ++r) {
                    int bb = mh * 32 + mt * 16 + q * 4 + r;
                    out[(size_t)B_ * T_ * D_ + (size_t)bb * H_ + n] = hv[r];
                }
            }
        }
    }
}

extern "C" void kernel_launch(void* const* d_in, const int* in_sizes, int n_in,
                              void* d_out, int out_size, void* d_ws, size_t ws_size,
                              hipStream_t stream) {
    const float* X    = (const float*)d_in[0];
    const float* Mm   = (const float*)d_in[1];
    const float* Wih0 = (const float*)d_in[2];
    const float* Whh0 = (const float*)d_in[3];
    const float* bih0 = (const float*)d_in[4];
    const float* bhh0 = (const float*)d_in[5];
    const float* Wih1 = (const float*)d_in[6];
    const float* Whh1 = (const float*)d_in[7];
    const float* bih1 = (const float*)d_in[8];
    const float* bhh1 = (const float*)d_in[9];
    const float* Wout = (const float*)d_in[10];
    const float* bout = (const float*)d_in[11];
    float* out = (float*)d_out;

    // ring workspace (256B aligned); no init: flags compare ==1 vs 0xAA
    // poison, hR slot 0 zeroed in-kernel by l1 blocks.
    char* ws = (char*)d_ws;
    size_t off = 0;
    auto alloc = [&](size_t bytes) { char* p = ws + off; off = (off + bytes + 255) & ~(size_t)255; return p; };
    unsigned short* hR   = (unsigned short*)alloc((size_t)(T_ + 1) * RS_H * 2);
    unsigned short* h0R  = (unsigned short*)alloc((size_t)T_ * RS_H * 2);
    unsigned short* impR = (unsigned short*)alloc((size_t)T_ * RS_IMP * 2);
    int*            fL1  = (int*)alloc((size_t)(T_ + 1) * 128 * 4);   // [t][mh][64]
    int*            fL0  = (int*)alloc((size_t)T_ * 128 * 4);         // [t][mh][64]
    int*            fE   = (int*)alloc((size_t)T_ * 128 * 4);         // [t][mh][64]

    k_fused<<<256, 256, 0, stream>>>(Wih0, Whh0, bih0, bhh0, Wih1, Whh1, bih1, bhh1,
                                     Wout, bout, X, Mm,
                                     hR, h0R, impR, fL1, fL0, fE, out);
}

// Round 2
// 2124.847 us; speedup vs baseline: 1.2440x; 1.0985x over previous
//
#include <hip/hip_runtime.h>
#include <math.h>

// MultiRNNCell: 2-layer LSTM-imputation scan. B=64, T=128, D=256, H=1024.
// R10 = R9 + est-first/register-keep (hides the fE hop) + packed publishes
//       + padded reduce strides (bank-conflict fix).
//  - L0est per step: pull h(t-1) K-half into a[16] regs -> est MFMAs only ->
//    publish imputed + signal fE EARLY -> replay a[] for 48 gate-h MFMAs
//    (hidden under the fE exchange) -> fE wait ~0 -> imp part -> h0 publish.
//  - All cross-block publishes go LDS->one-wave global_store_dwordx4 sc0 sc1
//    (1 VMEM op vs 8 of scattered 2B stores): faster drain, less MALL RMW.
//  - redE stride 5, redG stride 13 (coprime 32): no LDS bank conflicts.
// 256 blocks x 256 thr, ~138 KB LDS -> 1 block/CU.

#define B_ 64
#define T_ 128
#define D_ 256
#define H_ 1024

#define KS0 40          // layer0 frag ksteps: 0-7 imputed (D=256), 8-39 h (H=1024)
#define KS1 32          // layer1 ksteps (H=1024)

#define RS_H   ((size_t)B_ * H_)   // 128 KB per ring slot
#define RS_IMP ((size_t)B_ * D_)   // 32 KB per ring slot

typedef __attribute__((ext_vector_type(8))) short short8;   // 8 bf16
typedef __attribute__((ext_vector_type(4))) float floatx4;  // MFMA C/D
typedef __attribute__((ext_vector_type(4))) unsigned int uint4_;

__device__ __forceinline__ unsigned short f2bf(float x) {
    union { float f; unsigned u; } v; v.f = x;
    unsigned r = v.u + 0x7fffu + ((v.u >> 16) & 1u);  // RNE
    return (unsigned short)(r >> 16);
}
__device__ __forceinline__ float sigmoidf_(float x) { return 1.0f / (1.0f + expf(-x)); }

// write-through stores to the MALL coherence point (bypass L1+L2)
__device__ __forceinline__ void st_u64_sc(void* p, unsigned long long v) {
    asm volatile("global_store_dwordx2 %0, %1, off sc0 sc1"
                 :: "v"(p), "v"(v) : "memory");
}
__device__ __forceinline__ void st_u128_sc(void* p, uint4_ v) {
    asm volatile("global_store_dwordx4 %0, %1, off sc0 sc1"
                 :: "v"(p), "v"(v) : "memory");
}
__device__ __forceinline__ void vm_drain() {
    asm volatile("s_waitcnt vmcnt(0)" ::: "memory");
}

__device__ __forceinline__ void wait_ready(const int* flags, int P) {
    if ((int)threadIdx.x < P) {
        while (__hip_atomic_load(flags + threadIdx.x, __ATOMIC_RELAXED,
                                 __HIP_MEMORY_SCOPE_AGENT) != 1) {}
    }
    __syncthreads();
}
__device__ __forceinline__ void signal_flag(int* flag) {
    __syncthreads();    // storing wave's vm_drain precedes this barrier
    if (threadIdx.x == 0)
        __hip_atomic_store(flag, 1, __ATOMIC_RELAXED, __HIP_MEMORY_SCOPE_AGENT);
}

#define MFMA __builtin_amdgcn_mfma_f32_16x16x32_bf16

__global__ __launch_bounds__(256, 1) void k_fused(
    const float* __restrict__ Wih0, const float* __restrict__ Whh0,
    const float* __restrict__ bih0, const float* __restrict__ bhh0,
    const float* __restrict__ Wih1, const float* __restrict__ Whh1,
    const float* __restrict__ bih1, const float* __restrict__ bhh1,
    const float* __restrict__ Wout, const float* __restrict__ bout,
    const float* __restrict__ X, const float* __restrict__ Mm,
    unsigned short* __restrict__ hR,    // (T_+1) slots
    unsigned short* __restrict__ h0R,   // T_ slots
    unsigned short* __restrict__ impR,  // T_ slots
    int* __restrict__ fL1, int* __restrict__ fL0, int* __restrict__ fE,
    float* __restrict__ out)
{
    __shared__ unsigned short ldsW[3 * KS0 * 64 * 8];   // 120 KB weight frags
    __shared__ unsigned short ldsWo[32 * 16 * 8];       // 8 KB compact Wout (4 cols)
    __shared__ float redE[2 * 64 * 5];                  // est K-half reduce (pad 5)
    __shared__ float redG[2 * 64 * 13];                 // gate K-half reduce (pad 13)
    __shared__ unsigned short pub[32 * 16];             // 1 KB packed h publish
    __shared__ unsigned short impub[32 * 4];            // 256 B packed imp publish

    const int tid  = threadIdx.x;
    const int lane = tid & 63;
    const int wv   = tid >> 6;
    const int mt   = wv & 1;         // m-tile within the block's 32-row half
    const int kh   = wv >> 1;        // K-half this wave accumulates
    const int r16  = lane & 15, q = lane >> 4;
    const int bx   = blockIdx.x;
    const int rot  = (bx >> 3) & 7;  // XCD-local stagger (bx%8 = XCD id)
    const int rot2 = rot * 2;
    const unsigned short* lfrag = ldsW + lane * 8;   // + fragIdx*512

    if (bx < 128) {
        // =============== combined layer-0 + est blocks ===============
        const int j  = bx & 63;          // gate n-tile (cols 16j..16j+16)
        const int mh = bx >> 6;          // batch half (rows 32mh..32mh+32)
        const int rowA = mh * 32 + mt * 16 + r16;   // A-frag row for this wave
        {   // one-time: Wih0/Whh0 -> bf16 LDS frags (gates i,g,o; dead f removed)
            int n0 = j * 16;
            for (int idx = wv; idx < 3 * KS0; idx += 4) {
                int gi = idx / KS0, k = idx % KS0;
                int grow = (gi == 0) ? 0 : (gi == 1 ? 2 * H_ : 3 * H_);
                int row = grow + n0 + r16;
                const float* src = (k < 8) ? (Wih0 + (size_t)row * D_ + k * 32 + q * 8)
                                           : (Whh0 + (size_t)row * H_ + (k - 8) * 32 + q * 8);
                short8 w;
                #pragma unroll
                for (int e = 0; e < 8; ++e) w[e] = (short)f2bf(src[e]);
                *(short8*)(ldsW + ((size_t)idx * 64 + lane) * 8) = w;
            }
            // compact Wout slice: 4 est cols (dd = 4j..4j+3), slot = kk*16+c*4+q
            for (int s = tid; s < 512; s += 256) {
                int kk = s >> 4, c = (s >> 2) & 3, qq = s & 3;
                const float* src = Wout + (size_t)(4 * j + c) * H_ + kk * 32 + qq * 8;
                short8 w;
                #pragma unroll
                for (int e = 0; e < 8; ++e) w[e] = (short)f2bf(src[e]);
                *(short8*)(ldsWo + (size_t)s * 8) = w;
            }
        }
        __syncthreads();

        const int n = j * 16 + r16;
        const float bi = bih0[n] + bhh0[n];
        const float bg = bih0[2 * H_ + n] + bhh0[2 * H_ + n];
        const float bo = bih0[3 * H_ + n] + bhh0[3 * H_ + n];
        const int dd = 4 * j + (r16 & 3);           // est col (replicated x4)
        const float bout_d = bout[dd];
        const unsigned short* wofrag = ldsWo + ((r16 & 3) * 4 + q) * 8;

        for (int t = 0; t < T_; ++t) {
            float xv[4], mv[4];   // prefetch inputs before waiting
            if (kh == 0) {
                #pragma unroll
                for (int r = 0; r < 4; ++r) {
                    int bb = mh * 32 + mt * 16 + q * 4 + r;
                    xv[r] = X [((size_t)bb * T_ + t) * D_ + dd];
                    mv[r] = Mm[((size_t)bb * T_ + t) * D_ + dd];
                }
            }
            asm volatile("" ::: "memory");
            wait_ready(fL1 + ((size_t)t * 2 + mh) * 64, 64);   // h(t-1) half ready

            // ---- pull h(t-1) K-half into registers (issue all loads first) ----
            short8 a[16];
            const unsigned short* aB = hR + (size_t)t * RS_H + (size_t)rowA * H_ + q * 8;
            #pragma unroll
            for (int k = 0; k < 16; ++k) {
                int kk = kh * 16 + ((k + rot2) & 15);
                a[k] = *(const short8*)(aB + kk * 32);
            }
            // ---- est only: 16 MFMAs -> publish imputed ASAP ----
            floatx4 ae = {0.f,0.f,0.f,0.f};
            #pragma unroll
            for (int k = 0; k < 16; ++k) {
                int kk = kh * 16 + ((k + rot2) & 15);
                ae = MFMA(a[k], *(const short8*)(wofrag + kk * 128), ae, 0,0,0);
            }
            if (kh == 1) {
                float* rp = redE + ((size_t)mt * 64 + lane) * 5;
                #pragma unroll
                for (int r = 0; r < 4; ++r) rp[r] = ae[r];
            }
            __syncthreads();
            float estv[4];
            if (kh == 0) {
                const float* rp = redE + ((size_t)mt * 64 + lane) * 5;
                #pragma unroll
                for (int r = 0; r < 4; ++r) estv[r] = ae[r] + rp[r] + bout_d;
                if (r16 < 4) {
                    #pragma unroll
                    for (int r = 0; r < 4; ++r) {
                        float imp = mv[r] * xv[r] + (1.0f - mv[r]) * estv[r];
                        impub[(mt * 16 + q * 4 + r) * 4 + r16] = f2bf(imp);
                    }
                }
            }
            __syncthreads();
            if (wv == 0) {          // packed imp publish: 1 VMEM (32 x 8B)
                if (lane < 32) {
                    unsigned long long v = *(const unsigned long long*)(impub + lane * 4);
                    unsigned short* p = impR + (size_t)t * RS_IMP
                                      + (size_t)(mh * 32 + lane) * D_ + 4 * j;
                    st_u64_sc(p, v);
                }
                vm_drain();
            }
            signal_flag(fE + ((size_t)t * 2 + mh) * 64 + j);

            // ---- hidden phase: gate h-part from registers (no loads) ----
            floatx4 ai = {0.f,0.f,0.f,0.f}, ag = ai, ao = ai;
            #pragma unroll
            for (int k = 0; k < 16; ++k) {
                int kk = kh * 16 + ((k + rot2) & 15);
                ai = MFMA(a[k], *(const short8*)(lfrag + (0 * KS0 + 8 + kk) * 512), ai, 0,0,0);
                ag = MFMA(a[k], *(const short8*)(lfrag + (1 * KS0 + 8 + kk) * 512), ag, 0,0,0);
                ao = MFMA(a[k], *(const short8*)(lfrag + (2 * KS0 + 8 + kk) * 512), ao, 0,0,0);
            }
            // out est write: off the critical chain
            if (kh == 0 && r16 < 4 && t >= 1) {
                #pragma unroll
                for (int r = 0; r < 4; ++r) {
                    int bb = mh * 32 + mt * 16 + q * 4 + r;
                    out[((size_t)bb * T_ + (t - 1)) * D_ + dd] = estv[r];
                }
            }
            wait_ready(fE + ((size_t)t * 2 + mh) * 64, 64);    // likely already set
            {   // imputed part (this wave: 4 of 8 ksteps)
                const unsigned short* aB2 = impR + (size_t)t * RS_IMP + (size_t)rowA * D_ + q * 8;
                short8 ia[4];
                #pragma unroll
                for (int k = 0; k < 4; ++k) {
                    int kk = kh * 4 + ((k + rot) & 3);
                    ia[k] = *(const short8*)(aB2 + kk * 32);
                }
                #pragma unroll
                for (int k = 0; k < 4; ++k) {
                    int kk = kh * 4 + ((k + rot) & 3);
                    ai = MFMA(ia[k], *(const short8*)(lfrag + (0 * KS0 + kk) * 512), ai, 0,0,0);
                    ag = MFMA(ia[k], *(const short8*)(lfrag + (1 * KS0 + kk) * 512), ag, 0,0,0);
                    ao = MFMA(ia[k], *(const short8*)(lfrag + (2 * KS0 + kk) * 512), ao, 0,0,0);
                }
            }
            // gate K-half reduce -> h0 epilogue -> packed publish
            if (kh == 1) {
                float* rp = redG + ((size_t)mt * 64 + lane) * 13;
                #pragma unroll
                for (int r = 0; r < 4; ++r) { rp[r] = ai[r]; rp[4 + r] = ag[r]; rp[8 + r] = ao[r]; }
            }
            __syncthreads();
            if (kh == 0) {
                const float* rp = redG + ((size_t)mt * 64 + lane) * 13;
                #pragma unroll
                for (int r = 0; r < 4; ++r) {
                    float c = sigmoidf_(ai[r] + rp[r] + bi) * tanhf(ag[r] + rp[4 + r] + bg);
                    float h = sigmoidf_(ao[r] + rp[8 + r] + bo) * tanhf(c);
                    pub[(mt * 16 + q * 4 + r) * 16 + r16] = f2bf(h);
                }
            }
            __syncthreads();
            if (wv == 0) {          // packed h0 publish: 1 VMEM (64 x 16B)
                uint4_ v = *(const uint4_*)(pub + lane * 8);
                unsigned short* p = h0R + (size_t)t * RS_H
                                  + (size_t)(mh * 32 + (lane >> 1)) * H_ + j * 16 + (lane & 1) * 8;
                st_u128_sc(p, v);
                vm_drain();
            }
            signal_flag(fL0 + ((size_t)t * 2 + mh) * 64 + j);
        }
        // final projection: est from h(T-1) (slot T_) -> out[:, T-1, :]
        wait_ready(fL1 + ((size_t)T_ * 2 + mh) * 64, 64);
        short8 a[16];
        const unsigned short* aB = hR + (size_t)T_ * RS_H + (size_t)rowA * H_ + q * 8;
        #pragma unroll
        for (int k = 0; k < 16; ++k) {
            int kk = kh * 16 + ((k + rot2) & 15);
            a[k] = *(const short8*)(aB + kk * 32);
        }
        floatx4 ae = {0.f,0.f,0.f,0.f};
        #pragma unroll
        for (int k = 0; k < 16; ++k) {
            int kk = kh * 16 + ((k + rot2) & 15);
            ae = MFMA(a[k], *(const short8*)(wofrag + kk * 128), ae, 0,0,0);
        }
        if (kh == 1) {
            float* rp = redE + ((size_t)mt * 64 + lane) * 5;
            #pragma unroll
            for (int r = 0; r < 4; ++r) rp[r] = ae[r];
        }
        __syncthreads();
        if (kh == 0 && r16 < 4) {
            const float* rp = redE + ((size_t)mt * 64 + lane) * 5;
            #pragma unroll
            for (int r = 0; r < 4; ++r) {
                int bb = mh * 32 + mt * 16 + q * 4 + r;
                out[((size_t)bb * T_ + (T_ - 1)) * D_ + dd] = ae[r] + rp[r] + bout_d;
            }
        }
    } else {
        // =============== layer-1 blocks ===============
        const int i  = bx - 128;
        const int j1 = i & 63;           // n-tile
        const int mh = i >> 6;           // batch half
        const int rowA = mh * 32 + mt * 16 + r16;
        {   // one-time: folded W1 = Wih1+Whh1 -> bf16 LDS frags
            int n0 = j1 * 16;
            for (int idx = wv; idx < 3 * KS1; idx += 4) {
                int gi = idx / KS1, k = idx % KS1;
                int grow = (gi == 0) ? 0 : (gi == 1 ? 2 * H_ : 3 * H_);
                size_t o = (size_t)(grow + n0 + r16) * H_ + k * 32 + q * 8;
                short8 w;
                #pragma unroll
                for (int e = 0; e < 8; ++e) w[e] = (short)f2bf(Wih1[o + e] + Whh1[o + e]);
                *(short8*)(ldsW + ((size_t)idx * 64 + lane) * 8) = w;
            }
        }
        __syncthreads();
        const int n = j1 * 16 + r16;
        const float bi = bih1[n] + bhh1[n];
        const float bg = bih1[2 * H_ + n] + bhh1[2 * H_ + n];
        const float bo = bih1[3 * H_ + n] + bhh1[3 * H_ + n];
        // h(-1) = 0 -> packed zeros into hR slot 0, then flag it
        if (wv == 0) {
            uint4_ z = {0u, 0u, 0u, 0u};
            unsigned short* p = hR + (size_t)(mh * 32 + (lane >> 1)) * H_ + j1 * 16 + (lane & 1) * 8;
            st_u128_sc(p, z);
            vm_drain();
        }
        signal_flag(fL1 + (size_t)mh * 64 + j1);
        for (int t = 0; t < T_; ++t) {
            wait_ready(fL0 + ((size_t)t * 2 + mh) * 64, 64);   // h0(t) half ready
            short8 a[16];
            const unsigned short* aB = h0R + (size_t)t * RS_H + (size_t)rowA * H_ + q * 8;
            #pragma unroll
            for (int k = 0; k < 16; ++k) {
                int kk = kh * 16 + ((k + rot2) & 15);
                a[k] = *(const short8*)(aB + kk * 32);
            }
            floatx4 li = {0.f,0.f,0.f,0.f}, lg = li, lo = li;
            #pragma unroll
            for (int k = 0; k < 16; ++k) {
                int kk = kh * 16 + ((k + rot2) & 15);
                li = MFMA(a[k], *(const short8*)(lfrag + (0 * KS1 + kk) * 512), li, 0,0,0);
                lg = MFMA(a[k], *(const short8*)(lfrag + (1 * KS1 + kk) * 512), lg, 0,0,0);
                lo = MFMA(a[k], *(const short8*)(lfrag + (2 * KS1 + kk) * 512), lo, 0,0,0);
            }
            if (kh == 1) {
                float* rp = redG + ((size_t)mt * 64 + lane) * 13;
                #pragma unroll
                for (int r = 0; r < 4; ++r) { rp[r] = li[r]; rp[4 + r] = lg[r]; rp[8 + r] = lo[r]; }
            }
            __syncthreads();
            float hv[4];
            if (kh == 0) {
                const float* rp = redG + ((size_t)mt * 64 + lane) * 13;
                #pragma unroll
                for (int r = 0; r < 4; ++r) {
                    float c = sigmoidf_(li[r] + rp[r] + bi) * tanhf(lg[r] + rp[4 + r] + bg);
                    hv[r] = sigmoidf_(lo[r] + rp[8 + r] + bo) * tanhf(c);
                    pub[(mt * 16 + q * 4 + r) * 16 + r16] = f2bf(hv[r]);
                }
            }
            __syncthreads();
            if (wv == 0) {          // packed h publish: 1 VMEM (64 x 16B)
                uint4_ v = *(const uint4_*)(pub + lane * 8);
                unsigned short* p = hR + (size_t)(t + 1) * RS_H
                                  + (size_t)(mh * 32 + (lane >> 1)) * H_ + j1 * 16 + (lane & 1) * 8;
                st_u128_sc(p, v);
                vm_drain();
            }
            signal_flag(fL1 + ((size_t)(t + 1) * 2 + mh) * 64 + j1);
            if (t == T_ - 1 && kh == 0) {   // h_final, off the chain
                #pragma unroll
                for (int r = 0; r < 4; ++r) {
                    int bb = mh * 32 + mt * 16 + q * 4 + r;
                    out[(size_t)B_ * T_ * D_ + (size_t)bb * H_ + n] = hv[r];
                }
            }
        }
    }
}

extern "C" void kernel_launch(void* const* d_in, const int* in_sizes, int n_in,
                              void* d_out, int out_size, void* d_ws, size_t ws_size,
                              hipStream_t stream) {
    const float* X    = (const float*)d_in[0];
    const float* Mm   = (const float*)d_in[1];
    const float* Wih0 = (const float*)d_in[2];
    const float* Whh0 = (const float*)d_in[3];
    const float* bih0 = (const float*)d_in[4];
    const float* bhh0 = (const float*)d_in[5];
    const float* Wih1 = (const float*)d_in[6];
    const float* Whh1 = (const float*)d_in[7];
    const float* bih1 = (const float*)d_in[8];
    const float* bhh1 = (const float*)d_in[9];
    const float* Wout = (const float*)d_in[10];
    const float* bout = (const float*)d_in[11];
    float* out = (float*)d_out;

    // ring workspace (256B aligned); no init: flags compare ==1 vs 0xAA
    // poison, hR slot 0 zeroed in-kernel by l1 blocks.
    char* ws = (char*)d_ws;
    size_t off = 0;
    auto alloc = [&](size_t bytes) { char* p = ws + off; off = (off + bytes + 255) & ~(size_t)255; return p; };
    unsigned short* hR   = (unsigned short*)alloc((size_t)(T_ + 1) * RS_H * 2);
    unsigned short* h0R  = (unsigned short*)alloc((size_t)T_ * RS_H * 2);
    unsigned short* impR = (unsigned short*)alloc((size_t)T_ * RS_IMP * 2);
    int*            fL1  = (int*)alloc((size_t)(T_ + 1) * 128 * 4);   // [t][mh][64]
    int*            fL0  = (int*)alloc((size_t)T_ * 128 * 4);         // [t][mh][64]
    int*            fE   = (int*)alloc((size_t)T_ * 128 * 4);         // [t][mh][64]

    k_fused<<<256, 256, 0, stream>>>(Wih0, Whh0, bih0, bhh0, Wih1, Whh1, bih1, bhh1,
                                     Wout, bout, X, Mm,
                                     hR, h0R, impR, fL1, fL0, fE, out);
}